// Round 8
// baseline (186.153 us; speedup 1.0000x reference)
//
#include <hip/hip_runtime.h>
#include <stdint.h>

// Binarized ConvNet via XOR+popcount on packed bits.
// Round-8: kA writes the 25-bit conv1 windows DIRECTLY inside phase B
// (round-7 stashed them in a win4[4] array indexed by loop var — rule #20:
// runtime-indexed arrays can land in scratch; r6->r7 accounting showed +25us
// in kA for what should be a ~2us 6.4MB store).  kB reads win (L3-hot),
// rebuilds 32 channel outputs per position via popc vs wfilt, folds BN1
// thresholds -> bits, conv2 xor+popc b128 sliding window, direct coalesced
// ull stores in [n][i][64ch] layout.  BN thresholds per block by wave 0 +
// LDS broadcast (cross-block fence pattern costs ~73us/kernel — r1/r2).

#define NB 8192
typedef unsigned long long ull;

// ---- ws layout ----
#define OFF_WIN ((size_t)0)                    // u32 [NB][196] conv1 windows
#define SZ_WIN  ((size_t)NB*784)
#define OFF_C2  (OFF_WIN + SZ_WIN)             // ull [NB][8i][64ch] (o/2 bytes)
#define SZ_C2   ((size_t)NB*4096)
#define OFF_FC  (OFF_C2 + SZ_C2)               // int32 [NB][10]
#define SZ_FC   ((size_t)NB*10*4)
#define OFF_S1  (OFF_FC + SZ_FC)               // int  [8][32][2]   2048 B
#define OFF_S2  (OFF_S1 + 2048)                // ull  [8][64][2]   8192 B
#define OFF_S3  (OFF_S2 + 8192)                // ull  [8][10][2]   (pad 2048)
#define OFF_W2B (OFF_S3 + 2048)                // ull w2bT[8][64] (word-idx major)
#define OFF_W3B (OFF_W2B + 4096)               // ull w3b[10][64ch], bit=pos

// exact integer threshold: bit = (v >= T) ^ flip  <=>  s*v + t > 0
__device__ inline void mk_thresh(double s, double t, int &T, int &flip) {
    if (s > 0.0) {
        int v = (int)floor(-t / s) - 2;
        for (int c = 0; c < 6; ++c) { if (s * (double)v + t > 0.0) break; ++v; }
        T = v; flip = 0;
    } else if (s < 0.0) {
        int v = (int)floor(-t / s) - 2;
        for (int c = 0; c < 6; ++c) { if (!(s * (double)v + t > 0.0)) break; ++v; }
        T = v; flip = 1;
    } else { T = -200; flip = (t > 0.0) ? 0 : 1; }
}
__device__ inline int clampT(int T, int lim) {
    return (T < -lim) ? -lim : (T > lim) ? lim : T;
}

// ------------------------------------------------------------------
// KA: conv1 (binary) -> BN1 stats + 25-bit window dwords (6.4MB),
// windows stored straight from phase B (no stash array).
// 1 wave = 1 image, 4/block.  Blocks >= 2048: weight packer blocks.
// ------------------------------------------------------------------
__global__ __launch_bounds__(256) void kA_conv1(
    const float* __restrict__ x, const float* __restrict__ w1,
    const float* __restrict__ w2, const float* __restrict__ w3,
    uint32_t* __restrict__ winG, int* __restrict__ stats1,
    ull* __restrict__ w2bT, ull* __restrict__ w3b)
{
    const int tid = threadIdx.x, lane = tid & 63, wv = tid >> 6;

    if (blockIdx.x >= 2048) {   // ---- parallel weight packer blocks ----
        const int t = (blockIdx.x - 2048)*256 + tid;
        if (t < 512) {
            const int idx = t >> 6, k = t & 63;
            const int u = idx >> 1, pr = idx & 1;
            uint32_t lo = 0u, hi = 0u;
            #pragma unroll 8
            for (int c = 0; c < 32; ++c) {
                const float* wp = w2 + (((k*32 + c)*4 + u)*4 + 2*pr);
                lo |= (wp[0] > 0.f ? 1u : 0u) << c;
                hi |= (wp[1] > 0.f ? 1u : 0u) << c;
            }
            w2bT[t] = (ull)lo | ((ull)hi << 32);
        } else if (t < 1152) {
            const int w = t - 512;                 // w = m*64 + ch
            const float* wp = w3 + (size_t)(w >> 6)*4096 + (size_t)(w & 63)*64;
            ull bits = 0ull;
            #pragma unroll 16
            for (int k = 0; k < 64; ++k)
                bits |= (ull)(wp[k] > 0.f ? 1 : 0) << k;
            w3b[w] = bits;
        }
        return;
    }

    __shared__ ull sxb[4][16];              // 784 input sign bits, per wave
    __shared__ uint32_t wfilt[32];          // 25-bit filters
    __shared__ uint32_t outb[4][1568];      // int8 [196][32] as dwords, per wave
    __shared__ int lsum[32], lsq[32];

    if (tid < 32) {
        uint32_t f = 0u;
        #pragma unroll
        for (int q = 0; q < 25; ++q) f |= (w1[tid*25 + q] > 0.f ? 1u : 0u) << q;
        wfilt[tid] = f;
        lsum[tid] = 0; lsq[tid] = 0;
    }
    __syncthreads();          // barrier 1: wfilt + zeroed lsum visible
    const int n = blockIdx.x*4 + wv;
    // phase A: pack 784 input sign bits (13 ballot rounds) — wave-local
    #pragma unroll
    for (int t = 0; t < 13; ++t) {
        const int idx = t*64 + lane;
        const float v = (idx < 784) ? x[(size_t)n*784 + idx] : -1.f;
        const ull bal = __ballot(v > 0.f);
        if (lane == t) sxb[wv][t] = bal;
    }
    if (lane == 13) sxb[wv][13] = 0ull;
    // phase B: each lane computes up to 4 positions, 32 channels each;
    // window dword stored DIRECTLY to global (coalesced, no stash array).
    uint32_t* wdst = winG + (size_t)n*196;
    #pragma unroll
    for (int t = 0; t < 4; ++t) {
        const int p = t*64 + lane;
        if (p < 196) {
            const int i = p / 14, j = p - i*14;
            const uint32_t cmask = (j == 0) ? 0x1Cu : (j == 13) ? 0x0Fu : 0x1Fu;
            uint32_t win = 0u, vm = 0u;
            #pragma unroll
            for (int u = 0; u < 5; ++u) {
                const int r = 2*i + u - 2;
                if (r >= 0 && r < 28) {
                    const int bp = 28*r, w0 = bp >> 6, sh = bp & 63;
                    const ull a = sxb[wv][w0], b = sxb[wv][w0+1];
                    uint32_t row = (uint32_t)((a >> sh) | ((b << 1) << (63 - sh)));
                    row = (row & 0x0FFFFFFFu) << 2;
                    win |= ((row >> (2*j)) & 31u) << (5*u);
                    vm  |= cmask << (5*u);
                }
            }
            wdst[p] = win;
            const int nv = __popc(vm);
            uint32_t dw[8];
            #pragma unroll
            for (int d = 0; d < 8; ++d) dw[d] = 0u;
            #pragma unroll
            for (int c = 0; c < 32; ++c) {
                const int diff = __popc((win ^ wfilt[c]) & vm);
                const int o = nv - 2*diff;
                dw[c >> 2] |= (uint32_t)(o & 255) << (8*(c & 3));
            }
            #pragma unroll
            for (int d = 0; d < 8; ++d) outb[wv][p*8 + d] = dw[d];
        }
    }
    {   // stats: dword reads, lane owns channel-dword d = lane&7
        int s4[4] = {0,0,0,0}, q4[4] = {0,0,0,0};
        const uint32_t* ob32 = &outb[wv][0];
        #pragma unroll
        for (int t = 0; t < 25; ++t) {
            const int idx = t*64 + lane;
            if (idx < 1568) {
                const uint32_t dwv = ob32[idx];
                #pragma unroll
                for (int qq = 0; qq < 4; ++qq) {
                    const int v = (int)((int8_t)(dwv >> (8*qq)));
                    s4[qq] += v; q4[qq] += v*v;
                }
            }
        }
        #pragma unroll
        for (int off = 8; off <= 32; off <<= 1) {
            #pragma unroll
            for (int qq = 0; qq < 4; ++qq) {
                s4[qq] += __shfl_xor(s4[qq], off);
                q4[qq] += __shfl_xor(q4[qq], off);
            }
        }
        if (lane < 8) {
            #pragma unroll
            for (int qq = 0; qq < 4; ++qq) {
                atomicAdd(&lsum[lane*4 + qq], s4[qq]);
                atomicAdd(&lsq[lane*4 + qq], q4[qq]);
            }
        }
    }
    __syncthreads();          // barrier 2: all waves' stats in lsum/lsq
    if (tid < 32) {
        const int shard = blockIdx.x & 7;
        atomicAdd(&stats1[(shard*32 + tid)*2 + 0], lsum[tid]);
        atomicAdd(&stats1[(shard*32 + tid)*2 + 1], lsq[tid]);
    }
}

// ------------------------------------------------------------------
// KB: load win dwords (L3-hot, 6.4MB), rebuild 32 conv1 outputs per
// position via popc vs wfilt, fold per-BLOCK BN1 thresholds -> bits,
// then conv2 xor+popc with b128 register sliding window, direct
// coalesced ull stores in [n][i][64ch] layout.  1 wave = 1 image.
// ------------------------------------------------------------------
__global__ __launch_bounds__(256) void kB_conv2(
    const uint32_t* __restrict__ winG, const float* __restrict__ w1,
    const int* __restrict__ stats1,
    const float* __restrict__ gm1, const float* __restrict__ bt1,
    const ull* __restrict__ w2bT,
    ull* __restrict__ c2out, ull* __restrict__ stats2)
{
    __shared__ uint32_t wfilt[32];      // 25-bit conv1 filters
    __shared__ uint32_t BwU[4][14][16]; // packed conv1+BN1 bits, pad 16
    __shared__ int sT1[32];             // per-block thresholds
    __shared__ uint32_t sFlip1;
    __shared__ int ssum[64], ssq[64];
    const int tid = threadIdx.x, lane = tid & 63, wv = tid >> 6;
    const int n = blockIdx.x*4 + wv;

    // W fragments from global (coalesced, L2-hot), split lo/hi dwords
    uint32_t Wlo[8], Whi[8];
    #pragma unroll
    for (int idx = 0; idx < 8; ++idx) {
        const uint2 w = ((const uint2*)w2bT)[idx*64 + lane];
        Wlo[idx] = w.x; Whi[idx] = w.y;
    }

    if (tid < 64) { ssum[tid] = 0; ssq[tid] = 0; }
    // per-BLOCK: wave 0 packs conv1 filters AND computes BN1 thresholds
    int fl = 0;
    if (tid < 32) {
        uint32_t f = 0u;
        #pragma unroll
        for (int q = 0; q < 25; ++q) f |= (w1[tid*25 + q] > 0.f ? 1u : 0u) << q;
        wfilt[tid] = f;
        long long s = 0, q = 0;
        for (int sh = 0; sh < 8; ++sh) {
            s += stats1[(sh*32 + tid)*2 + 0];
            q += stats1[(sh*32 + tid)*2 + 1];
        }
        const double N = 8192.0 * 196.0;
        const double mean = (double)s / N;
        const double var  = (double)q / N - mean*mean;
        const double a = (double)gm1[tid] / sqrt(var + 1e-5);
        const double b = (double)bt1[tid] - mean*a;
        int T; mk_thresh(a, b, T, fl);
        sT1[tid] = clampT(T, 26);
    }
    if (wv == 0) {
        const uint32_t fn1 = ~(uint32_t)__ballot(fl != 0);
        if (lane == 0) sFlip1 = fn1;
    }
    __syncthreads();          // wfilt + sT1 + sFlip1 + ssum zeros visible
    const uint32_t flipn1 = sFlip1;

    // pack phase: win dword -> 32 channel outputs -> threshold bits.
    // vm/nv are position-only (recomputed, no data dependence).
    for (int t = lane; t < 196; t += 64) {
        const int i = t / 14, j = t - i*14;
        const uint32_t cmask = (j == 0) ? 0x1Cu : (j == 13) ? 0x0Fu : 0x1Fu;
        uint32_t vm = 0u;
        #pragma unroll
        for (int u = 0; u < 5; ++u) {
            const int r = 2*i + u - 2;
            if (r >= 0 && r < 28) vm |= cmask << (5*u);
        }
        const int nv = __popc(vm);
        const uint32_t win = winG[(size_t)n*196 + t];
        uint32_t neg = 0u;
        #pragma unroll
        for (int c = 0; c < 32; ++c) {
            const int diff = __popc((win ^ wfilt[c]) & vm);
            const int o = nv - 2*diff;
            neg |= ((uint32_t)(o - sT1[c]) >> 31) << c;   // 1 iff o<T
        }
        BwU[wv][i][j] = neg ^ flipn1;
    }

    // compute phase: lane = out-channel; b128 register sliding window.
    // pair k = rows (2k, 2k+1); output row i uses pair i-1 (u=0,1) and pair i
    // (u=2,3).  Rows read ONCE via 4x ds_read_b128 each (wave-uniform bcast).
    uint32_t PA[32], PB[32];
#define LOADP(BUF, K)                                                          \
    {                                                                          \
        const uint4* r0 = (const uint4*)&BwU[wv][2*(K)][0];                    \
        const uint4* r1 = (const uint4*)&BwU[wv][2*(K)+1][0];                  \
        _Pragma("unroll")                                                      \
        for (int tt = 0; tt < 4; ++tt) {                                       \
            const uint4 v0 = r0[tt];                                           \
            BUF[4*tt+0] = v0.x; BUF[4*tt+1] = v0.y;                            \
            BUF[4*tt+2] = v0.z; BUF[4*tt+3] = v0.w;                            \
            const uint4 v1 = r1[tt];                                           \
            BUF[16+4*tt+0] = v1.x; BUF[16+4*tt+1] = v1.y;                      \
            BUF[16+4*tt+2] = v1.z; BUF[16+4*tt+3] = v1.w;                      \
        }                                                                      \
    }
#define UT(BUF, RO, UU)                                                        \
    {                                                                          \
        if (j >= 1) { D += __popc(BUF[(RO)*16 + 2*j-2] ^ Wlo[2*(UU)])          \
                         + __popc(BUF[(RO)*16 + 2*j-1] ^ Whi[2*(UU)]);   ++nw; } \
        if (j <= 6) { D += __popc(BUF[(RO)*16 + 2*j]   ^ Wlo[2*(UU)+1])        \
                         + __popc(BUF[(RO)*16 + 2*j+1] ^ Whi[2*(UU)+1]); ++nw; } \
    }
    int s = 0, q = 0;
    ull* dst = c2out + (size_t)n*512 + lane;     // [n][i][64ch] ull layout
    LOADP(PA, 0)
    #pragma unroll
    for (int i = 0; i < 8; ++i) {
        if (i >= 1 && i <= 6) {      // prefetch pair i into alternating buffer
            if (i & 1) { LOADP(PB, i) } else { LOADP(PA, i) }
        }
        uint32_t o0 = 0u, o1 = 0u;
        #pragma unroll
        for (int j = 0; j < 8; ++j) {
            int D = 0, nw = 0;
            if (i >= 1) {            // pair i-1: rows 2i-2 (u=0), 2i-1 (u=1)
                if ((i-1) & 1) { UT(PB, 0, 0) UT(PB, 1, 1) }
                else           { UT(PA, 0, 0) UT(PA, 1, 1) }
            }
            if (i <= 6) {            // pair i:   rows 2i (u=2), 2i+1 (u=3)
                if (i & 1) { UT(PB, 0, 2) UT(PB, 1, 3) }
                else       { UT(PA, 0, 2) UT(PA, 1, 3) }
            }
            const int o = 32*nw - D;         // = full/2, exact
            s += o; q += o*o;
            if (j < 4) o0 |= (uint32_t)(o & 255) << (8*j);
            else       o1 |= (uint32_t)(o & 255) << (8*(j-4));
        }
        // direct coalesced store: consecutive lanes -> consecutive 8B
        dst[i*64] = (ull)o0 | ((ull)o1 << 32);
    }
#undef LOADP
#undef UT
    atomicAdd(&ssum[lane], s);
    atomicAdd(&ssq[lane], q);
    __syncthreads();          // barrier 2: all waves' stats in ssum/ssq
    if (tid < 64) {
        const int shard = blockIdx.x & 7;
        atomicAdd(&stats2[(shard*64 + tid)*2 + 0], (ull)(long long)ssum[tid]);
        atomicAdd(&stats2[(shard*64 + tid)*2 + 1], (ull)(long long)ssq[tid]);
    }
}

// ------------------------------------------------------------------
// KC: per-BLOCK BN2 thresholds (wave 0 computes lane=ch, LDS broadcast),
// binarize arithmetically from [n][i][64ch] ull layout, fc xor+popc,
// packed shuffle reduction, BN3 stats.  1 wave = 1 image.
// ------------------------------------------------------------------
__global__ __launch_bounds__(256) void kC_fc(
    const ull* __restrict__ c2o, const float* __restrict__ gm2,
    const float* __restrict__ bt2, const ull* __restrict__ stats2,
    const ull* __restrict__ w3b,
    int* __restrict__ fc, ull* __restrict__ stats3)
{
    __shared__ int fco[4][10];
    __shared__ int s3[10], q3[10];
    __shared__ int sT2[64];
    __shared__ ull sFlip2;
    const int tid = threadIdx.x, lane = tid & 63, wv = tid >> 6;
    if (tid < 10) { s3[tid] = 0; q3[tid] = 0; }
    // per-BLOCK BN2 thresholds: wave 0, lane = channel (4x less than per-wave)
    if (wv == 0) {
        long long ss = 0, qq = 0;
        for (int sh = 0; sh < 8; ++sh) {
            ss += (long long)stats2[(sh*64 + lane)*2 + 0];
            qq += (long long)stats2[(sh*64 + lane)*2 + 1];
        }
        const double N = 8192.0 * 64.0;
        const double mh = (double)ss / N;
        const double vh = (double)qq / N - mh*mh;
        const double a = (double)gm2[lane] / sqrt(4.0*vh + 1e-5);
        const double b = (double)bt2[lane] - 2.0*mh*a;
        int T, fl; mk_thresh(2.0*a, b, T, fl);
        sT2[lane] = clampT(T, 200);
        const ull fn2 = ~__ballot(fl != 0);
        if (lane == 0) sFlip2 = fn2;
    }
    __syncthreads();          // sT2 + sFlip2 + s3/q3 zeros visible
    const int T2 = sT2[lane];
    const ull flipn2 = sFlip2;
    const int n = blockIdx.x*4 + wv;
    // load own channel's 8 ull rows (coalesced: consecutive lanes 8B apart),
    // build bit-word arithmetically; byte b of row i = position i*8+b
    const ull* src = c2o + (size_t)n*512 + lane;
    uint32_t neglo = 0u, neghi = 0u;
    #pragma unroll
    for (int ii = 0; ii < 8; ++ii) {
        const ull v8 = src[(size_t)ii*64];
        const uint32_t w0 = (uint32_t)v8, w1 = (uint32_t)(v8 >> 32);
        uint32_t b8 = 0u;
        #pragma unroll
        for (int b = 0; b < 4; ++b) {
            const int v0 = (int)((int8_t)(w0 >> (8*b)));
            b8 |= ((uint32_t)(v0 - T2) >> 31) << b;          // 1 iff v<T
            const int v1 = (int)((int8_t)(w1 >> (8*b)));
            b8 |= ((uint32_t)(v1 - T2) >> 31) << (4 + b);
        }
        if (ii < 4) neglo |= b8 << (8*ii); else neghi |= b8 << (8*(ii-4));
    }
    const ull myw = ((ull)neglo | ((ull)neghi << 32)) ^ flipn2;
    // 10 outputs: popc of mismatch vs w3 words (global, L2-hot), packed reduce
    uint32_t pk[5];
    #pragma unroll
    for (int t = 0; t < 5; ++t) {
        const uint32_t pa = (uint32_t)__popcll(myw ^ w3b[(2*t+0)*64 + lane]);
        const uint32_t pb = (uint32_t)__popcll(myw ^ w3b[(2*t+1)*64 + lane]);
        pk[t] = pa | (pb << 16);
    }
    #pragma unroll
    for (int off = 32; off >= 1; off >>= 1) {
        #pragma unroll
        for (int t = 0; t < 5; ++t) pk[t] += __shfl_xor(pk[t], off);
    }
    if (lane == 0) {
        #pragma unroll
        for (int m = 0; m < 10; ++m) {
            const int tot = (pk[m >> 1] >> (16*(m & 1))) & 0xFFFF;
            fco[wv][m] = 4096 - 2*tot;
        }
    }
    __syncthreads();
    if (tid < 40) {
        const int li = tid / 10, m = tid - li*10;
        const int o = fco[li][m];
        fc[(size_t)(blockIdx.x*4 + li)*10 + m] = o;
        atomicAdd(&s3[m], o);
        atomicAdd(&q3[m], o*o);
    }
    __syncthreads();
    if (tid < 10) {
        const int shard = blockIdx.x & 7;
        atomicAdd(&stats3[(shard*10 + tid)*2 + 0], (ull)(long long)s3[tid]);
        atomicAdd(&stats3[(shard*10 + tid)*2 + 1], (ull)(long long)q3[tid]);
    }
}

// ------------------------------------------------------------------
// KD: reduce BN3 stats (per block, redundant) + apply -> d_out (fp32)
// ------------------------------------------------------------------
__global__ __launch_bounds__(256) void kD_apply(
    const int* __restrict__ fc, const float* __restrict__ gm3,
    const float* __restrict__ bt3, const ull* __restrict__ stats3,
    float* __restrict__ out)
{
    __shared__ float a3[10], b3[10];
    const int tid = threadIdx.x;
    if (tid < 10) {
        long long s = 0, q = 0;
        for (int sh = 0; sh < 8; ++sh) {
            s += (long long)stats3[(sh*10 + tid)*2 + 0];
            q += (long long)stats3[(sh*10 + tid)*2 + 1];
        }
        const double N = 8192.0;
        const double mean = (double)s / N;
        const double var  = (double)q / N - mean*mean;
        const double a = (double)gm3[tid] / sqrt(var + 1e-5);
        a3[tid] = (float)a;
        b3[tid] = (float)((double)bt3[tid] - mean*a);
    }
    __syncthreads();
    const int e = blockIdx.x*256 + tid;
    if (e < NB*10) {
        const int m = e % 10;
        out[e] = fmaf(a3[m], (float)fc[e], b3[m]);
    }
}

extern "C" void kernel_launch(void* const* d_in, const int* in_sizes, int n_in,
                              void* d_out, int out_size, void* d_ws, size_t ws_size,
                              hipStream_t stream)
{
    const float* x   = (const float*)d_in[0];
    const float* w1  = (const float*)d_in[1];
    const float* gm1 = (const float*)d_in[2];
    const float* bt1 = (const float*)d_in[3];
    const float* w2  = (const float*)d_in[4];
    const float* gm2 = (const float*)d_in[5];
    const float* bt2 = (const float*)d_in[6];
    const float* w3  = (const float*)d_in[7];
    const float* gm3 = (const float*)d_in[8];
    const float* bt3 = (const float*)d_in[9];
    char* ws = (char*)d_ws;
    uint32_t* wing = (uint32_t*)(ws + OFF_WIN);
    ull*    c2o = (ull*)(ws + OFF_C2);
    int*    fcb = (int*)(ws + OFF_FC);
    int*    s1  = (int*)(ws + OFF_S1);
    ull*    s2  = (ull*)(ws + OFF_S2);
    ull*    s3  = (ull*)(ws + OFF_S3);
    ull*    w2bp = (ull*)(ws + OFF_W2B);
    ull*    w3bp = (ull*)(ws + OFF_W3B);

    (void)hipMemsetAsync(ws + OFF_S1, 0, 12288, stream);
    kA_conv1<<<2053, 256, 0, stream>>>(x, w1, w2, w3, wing, s1, w2bp, w3bp);
    kB_conv2<<<2048, 256, 0, stream>>>(wing, w1, s1, gm1, bt1, w2bp, c2o, s2);
    kC_fc   <<<2048, 256, 0, stream>>>(c2o, gm2, bt2, s2, w3bp, fcb, s3);
    kD_apply<<<320,  256, 0, stream>>>(fcb, gm3, bt3, s3, (float*)d_out);
}

// Round 9
// 185.190 us; speedup vs baseline: 1.0052x; 1.0052x over previous
//
#include <hip/hip_runtime.h>
#include <stdint.h>

// Binarized ConvNet via XOR+popcount on packed bits.  (r5 structure.)
// Round-9: INSTRUMENTATION round.  kB split into two half-grid launches so
// kA/kC finally surface in the rocprof top-5 (they have never been measured;
// three inconsistent cost models survive r0-r8 accounting).  Perf predicted
// neutral vs r5 (182.6us).  BN thresholds per block by wave 0 + LDS
// broadcast (cross-block fence pattern costs ~73us/kernel — r1/r2).
// kB conv2 output: [n][i][64ch] ull layout, direct coalesced 512B stores.

#define NB 8192
typedef unsigned long long ull;

// ---- ws layout ----
#define OFF_C1  ((size_t)0)                    // int8 [NB][196pos][32ch]
#define SZ_C1   ((size_t)NB*6272)
#define OFF_C2  (OFF_C1 + SZ_C1)               // ull [NB][8i][64ch] (o/2 bytes)
#define SZ_C2   ((size_t)NB*4096)
#define OFF_FC  (OFF_C2 + SZ_C2)               // int32 [NB][10]
#define SZ_FC   ((size_t)NB*10*4)
#define OFF_S1  (OFF_FC + SZ_FC)               // int  [8][32][2]   2048 B
#define OFF_S2  (OFF_S1 + 2048)                // ull  [8][64][2]   8192 B
#define OFF_S3  (OFF_S2 + 8192)                // ull  [8][10][2]   (pad 2048)
#define OFF_W2B (OFF_S3 + 2048)                // ull w2bT[8][64] (word-idx major)
#define OFF_W3B (OFF_W2B + 4096)               // ull w3b[10][64ch], bit=pos

// exact integer threshold: bit = (v >= T) ^ flip  <=>  s*v + t > 0
__device__ inline void mk_thresh(double s, double t, int &T, int &flip) {
    if (s > 0.0) {
        int v = (int)floor(-t / s) - 2;
        for (int c = 0; c < 6; ++c) { if (s * (double)v + t > 0.0) break; ++v; }
        T = v; flip = 0;
    } else if (s < 0.0) {
        int v = (int)floor(-t / s) - 2;
        for (int c = 0; c < 6; ++c) { if (!(s * (double)v + t > 0.0)) break; ++v; }
        T = v; flip = 1;
    } else { T = -200; flip = (t > 0.0) ? 0 : 1; }
}
__device__ inline int clampT(int T, int lim) {
    return (T < -lim) ? -lim : (T > lim) ? lim : T;
}

// ------------------------------------------------------------------
// KA: conv1 (binary) + integer BN1 stats + c1 write.  1 wave = 1 image,
// 4/block.  Blocks >= 2048: weight packer, one THREAD per packed word.
// ------------------------------------------------------------------
__global__ __launch_bounds__(256) void kA_conv1(
    const float* __restrict__ x, const float* __restrict__ w1,
    const float* __restrict__ w2, const float* __restrict__ w3,
    int8_t* __restrict__ c1out, int* __restrict__ stats1,
    ull* __restrict__ w2bT, ull* __restrict__ w3b)
{
    const int tid = threadIdx.x, lane = tid & 63, wv = tid >> 6;

    if (blockIdx.x >= 2048) {   // ---- parallel weight packer blocks ----
        const int t = (blockIdx.x - 2048)*256 + tid;
        if (t < 512) {
            const int idx = t >> 6, k = t & 63;
            const int u = idx >> 1, pr = idx & 1;
            uint32_t lo = 0u, hi = 0u;
            #pragma unroll 8
            for (int c = 0; c < 32; ++c) {
                const float* wp = w2 + (((k*32 + c)*4 + u)*4 + 2*pr);
                lo |= (wp[0] > 0.f ? 1u : 0u) << c;
                hi |= (wp[1] > 0.f ? 1u : 0u) << c;
            }
            w2bT[t] = (ull)lo | ((ull)hi << 32);
        } else if (t < 1152) {
            const int w = t - 512;                 // w = m*64 + ch
            const float* wp = w3 + (size_t)(w >> 6)*4096 + (size_t)(w & 63)*64;
            ull bits = 0ull;
            #pragma unroll 16
            for (int k = 0; k < 64; ++k)
                bits |= (ull)(wp[k] > 0.f ? 1 : 0) << k;
            w3b[w] = bits;
        }
        return;
    }

    __shared__ ull sxb[4][16];              // 784 input sign bits, per wave
    __shared__ uint32_t wfilt[32];          // 25-bit filters
    __shared__ uint32_t outb[4][1568];      // int8 [196][32] as dwords, per wave
    __shared__ int lsum[32], lsq[32];

    if (tid < 32) {
        uint32_t f = 0u;
        #pragma unroll
        for (int q = 0; q < 25; ++q) f |= (w1[tid*25 + q] > 0.f ? 1u : 0u) << q;
        wfilt[tid] = f;
        lsum[tid] = 0; lsq[tid] = 0;
    }
    __syncthreads();          // barrier 1: wfilt + zeroed lsum visible
    const int n = blockIdx.x*4 + wv;
    // phase A: pack 784 input sign bits (13 ballot rounds) — wave-local
    #pragma unroll
    for (int t = 0; t < 13; ++t) {
        const int idx = t*64 + lane;
        const float v = (idx < 784) ? x[(size_t)n*784 + idx] : -1.f;
        const ull bal = __ballot(v > 0.f);
        if (lane == t) sxb[wv][t] = bal;
    }
    if (lane == 13) sxb[wv][13] = 0ull;
    // phase B: each lane computes up to 4 positions, 32 channels each
    for (int t = 0; t < 4; ++t) {
        const int p = t*64 + lane;
        if (p < 196) {
            const int i = p / 14, j = p - i*14;
            const uint32_t cmask = (j == 0) ? 0x1Cu : (j == 13) ? 0x0Fu : 0x1Fu;
            uint32_t win = 0u, vm = 0u;
            #pragma unroll
            for (int u = 0; u < 5; ++u) {
                const int r = 2*i + u - 2;
                if (r >= 0 && r < 28) {
                    const int bp = 28*r, w0 = bp >> 6, sh = bp & 63;
                    const ull a = sxb[wv][w0], b = sxb[wv][w0+1];
                    uint32_t row = (uint32_t)((a >> sh) | ((b << 1) << (63 - sh)));
                    row = (row & 0x0FFFFFFFu) << 2;
                    win |= ((row >> (2*j)) & 31u) << (5*u);
                    vm  |= cmask << (5*u);
                }
            }
            const int nv = __popc(vm);
            uint32_t dw[8];
            #pragma unroll
            for (int d = 0; d < 8; ++d) dw[d] = 0u;
            #pragma unroll
            for (int c = 0; c < 32; ++c) {
                const int diff = __popc((win ^ wfilt[c]) & vm);
                const int o = nv - 2*diff;
                dw[c >> 2] |= (uint32_t)(o & 255) << (8*(c & 3));
            }
            #pragma unroll
            for (int d = 0; d < 8; ++d) outb[wv][p*8 + d] = dw[d];
        }
    }
    {   // coalesced write [n][pos][ch] — wave-local, from LDS staging
        int4* dst = (int4*)(c1out + (size_t)n*6272);
        const int4* src = (const int4*)&outb[wv][0];
        #pragma unroll
        for (int t = 0; t < 7; ++t) {
            const int idx = t*64 + lane;
            if (idx < 392) dst[idx] = src[idx];
        }
    }
    {   // stats: dword reads, lane owns channel-dword d = lane&7
        int s4[4] = {0,0,0,0}, q4[4] = {0,0,0,0};
        const uint32_t* ob32 = &outb[wv][0];
        #pragma unroll
        for (int t = 0; t < 25; ++t) {
            const int idx = t*64 + lane;
            if (idx < 1568) {
                const uint32_t dwv = ob32[idx];
                #pragma unroll
                for (int qq = 0; qq < 4; ++qq) {
                    const int v = (int)((int8_t)(dwv >> (8*qq)));
                    s4[qq] += v; q4[qq] += v*v;
                }
            }
        }
        #pragma unroll
        for (int off = 8; off <= 32; off <<= 1) {
            #pragma unroll
            for (int qq = 0; qq < 4; ++qq) {
                s4[qq] += __shfl_xor(s4[qq], off);
                q4[qq] += __shfl_xor(q4[qq], off);
            }
        }
        if (lane < 8) {
            #pragma unroll
            for (int qq = 0; qq < 4; ++qq) {
                atomicAdd(&lsum[lane*4 + qq], s4[qq]);
                atomicAdd(&lsq[lane*4 + qq], q4[qq]);
            }
        }
    }
    __syncthreads();          // barrier 2: all waves' stats in lsum/lsq
    if (tid < 32) {
        const int shard = blockIdx.x & 7;
        atomicAdd(&stats1[(shard*32 + tid)*2 + 0], lsum[tid]);
        atomicAdd(&stats1[(shard*32 + tid)*2 + 1], lsq[tid]);
    }
}

// ------------------------------------------------------------------
// KB: per-BLOCK BN1 thresholds (wave 0 computes, LDS broadcast), binarize
// c1, conv2 xor+popc with b128 register sliding window, direct coalesced
// ull stores in [n][i][64ch] layout.  1 wave = 1 image.  Half-grid: the
// launch passes n0 (0 or NB/2); 1024 blocks each.
// ------------------------------------------------------------------
__global__ __launch_bounds__(256) void kB_conv2(
    const int8_t* __restrict__ c1out, const int* __restrict__ stats1,
    const float* __restrict__ gm1, const float* __restrict__ bt1,
    const ull* __restrict__ w2bT,
    ull* __restrict__ c2out, ull* __restrict__ stats2, int n0)
{
    __shared__ uint32_t BwU[4][14][16]; // packed input bits, 14 used/row, pad 16
    __shared__ int sT1[32];             // per-block thresholds
    __shared__ uint32_t sFlip1;
    __shared__ int ssum[64], ssq[64];
    const int tid = threadIdx.x, lane = tid & 63, wv = tid >> 6;
    const int n = n0 + blockIdx.x*4 + wv;

    // W fragments from global (coalesced, L2-hot), split lo/hi dwords
    uint32_t Wlo[8], Whi[8];
    #pragma unroll
    for (int idx = 0; idx < 8; ++idx) {
        const uint2 w = ((const uint2*)w2bT)[idx*64 + lane];
        Wlo[idx] = w.x; Whi[idx] = w.y;
    }

    if (tid < 64) { ssum[tid] = 0; ssq[tid] = 0; }
    // per-BLOCK BN1 threshold computation (wave 0 only)
    int fl = 0;
    if (tid < 32) {
        long long s = 0, q = 0;
        for (int sh = 0; sh < 8; ++sh) {
            s += stats1[(sh*32 + tid)*2 + 0];
            q += stats1[(sh*32 + tid)*2 + 1];
        }
        const double N = 8192.0 * 196.0;
        const double mean = (double)s / N;
        const double var  = (double)q / N - mean*mean;
        const double a = (double)gm1[tid] / sqrt(var + 1e-5);
        const double b = (double)bt1[tid] - mean*a;
        int T; mk_thresh(a, b, T, fl);
        sT1[tid] = clampT(T, 26);
    }
    if (wv == 0) {
        const uint32_t fn1 = ~(uint32_t)__ballot(fl != 0);
        if (lane == 0) sFlip1 = fn1;
    }
    __syncthreads();          // barrier 1: sT1 + sFlip1 + ssum zeros visible
    const uint32_t flipn1 = sFlip1;

    // pack phase — wave-local: binarize own image's 196 positions
    for (int t = lane; t < 196; t += 64) {
        const int r = t / 14, c = t - r*14;
        const uint4* src = (const uint4*)(c1out + ((size_t)n*196 + t)*32);
        const uint4 lo4 = src[0], hi4 = src[1];
        const uint32_t wsrc[8] = {lo4.x, lo4.y, lo4.z, lo4.w, hi4.x, hi4.y, hi4.z, hi4.w};
        uint32_t neg = 0u;
        #pragma unroll
        for (int d = 0; d < 8; ++d) {
            #pragma unroll
            for (int qq = 0; qq < 4; ++qq) {
                const int ch = d*4 + qq;
                const int v = (int)((int8_t)(wsrc[d] >> (8*qq)));
                neg |= ((uint32_t)(v - sT1[ch]) >> 31) << ch;   // 1 iff v<T
            }
        }
        BwU[wv][r][c] = neg ^ flipn1;
    }

    // compute phase: lane = out-channel; b128 register sliding window.
    uint32_t PA[32], PB[32];
#define LOADP(BUF, K)                                                          \
    {                                                                          \
        const uint4* r0 = (const uint4*)&BwU[wv][2*(K)][0];                    \
        const uint4* r1 = (const uint4*)&BwU[wv][2*(K)+1][0];                  \
        _Pragma("unroll")                                                      \
        for (int tt = 0; tt < 4; ++tt) {                                       \
            const uint4 v0 = r0[tt];                                           \
            BUF[4*tt+0] = v0.x; BUF[4*tt+1] = v0.y;                            \
            BUF[4*tt+2] = v0.z; BUF[4*tt+3] = v0.w;                            \
            const uint4 v1 = r1[tt];                                           \
            BUF[16+4*tt+0] = v1.x; BUF[16+4*tt+1] = v1.y;                      \
            BUF[16+4*tt+2] = v1.z; BUF[16+4*tt+3] = v1.w;                      \
        }                                                                      \
    }
#define UT(BUF, RO, UU)                                                        \
    {                                                                          \
        if (j >= 1) { D += __popc(BUF[(RO)*16 + 2*j-2] ^ Wlo[2*(UU)])          \
                         + __popc(BUF[(RO)*16 + 2*j-1] ^ Whi[2*(UU)]);   ++nw; } \
        if (j <= 6) { D += __popc(BUF[(RO)*16 + 2*j]   ^ Wlo[2*(UU)+1])        \
                         + __popc(BUF[(RO)*16 + 2*j+1] ^ Whi[2*(UU)+1]); ++nw; } \
    }
    int s = 0, q = 0;
    ull* dst = c2out + (size_t)n*512 + lane;     // [n][i][64ch] ull layout
    LOADP(PA, 0)
    #pragma unroll
    for (int i = 0; i < 8; ++i) {
        if (i >= 1 && i <= 6) {      // prefetch pair i into alternating buffer
            if (i & 1) { LOADP(PB, i) } else { LOADP(PA, i) }
        }
        uint32_t o0 = 0u, o1 = 0u;
        #pragma unroll
        for (int j = 0; j < 8; ++j) {
            int D = 0, nw = 0;
            if (i >= 1) {            // pair i-1: rows 2i-2 (u=0), 2i-1 (u=1)
                if ((i-1) & 1) { UT(PB, 0, 0) UT(PB, 1, 1) }
                else           { UT(PA, 0, 0) UT(PA, 1, 1) }
            }
            if (i <= 6) {            // pair i:   rows 2i (u=2), 2i+1 (u=3)
                if (i & 1) { UT(PB, 0, 2) UT(PB, 1, 3) }
                else       { UT(PA, 0, 2) UT(PA, 1, 3) }
            }
            const int o = 32*nw - D;         // = full/2, exact
            s += o; q += o*o;
            if (j < 4) o0 |= (uint32_t)(o & 255) << (8*j);
            else       o1 |= (uint32_t)(o & 255) << (8*(j-4));
        }
        // direct coalesced store: consecutive lanes -> consecutive 8B
        dst[i*64] = (ull)o0 | ((ull)o1 << 32);
    }
#undef LOADP
#undef UT
    atomicAdd(&ssum[lane], s);
    atomicAdd(&ssq[lane], q);
    __syncthreads();          // barrier 2: all waves' stats in ssum/ssq
    if (tid < 64) {
        const int shard = blockIdx.x & 7;
        atomicAdd(&stats2[(shard*64 + tid)*2 + 0], (ull)(long long)ssum[tid]);
        atomicAdd(&stats2[(shard*64 + tid)*2 + 1], (ull)(long long)ssq[tid]);
    }
}

// ------------------------------------------------------------------
// KC: per-BLOCK BN2 thresholds (wave 0 computes lane=ch, LDS broadcast),
// binarize arithmetically from [n][i][64ch] ull layout, fc xor+popc,
// packed shuffle reduction, BN3 stats.  1 wave = 1 image.
// ------------------------------------------------------------------
__global__ __launch_bounds__(256) void kC_fc(
    const ull* __restrict__ c2o, const float* __restrict__ gm2,
    const float* __restrict__ bt2, const ull* __restrict__ stats2,
    const ull* __restrict__ w3b,
    int* __restrict__ fc, ull* __restrict__ stats3)
{
    __shared__ int fco[4][10];
    __shared__ int s3[10], q3[10];
    __shared__ int sT2[64];
    __shared__ ull sFlip2;
    const int tid = threadIdx.x, lane = tid & 63, wv = tid >> 6;
    if (tid < 10) { s3[tid] = 0; q3[tid] = 0; }
    // per-BLOCK BN2 thresholds: wave 0, lane = channel
    if (wv == 0) {
        long long ss = 0, qq = 0;
        for (int sh = 0; sh < 8; ++sh) {
            ss += (long long)stats2[(sh*64 + lane)*2 + 0];
            qq += (long long)stats2[(sh*64 + lane)*2 + 1];
        }
        const double N = 8192.0 * 64.0;
        const double mh = (double)ss / N;
        const double vh = (double)qq / N - mh*mh;
        const double a = (double)gm2[lane] / sqrt(4.0*vh + 1e-5);
        const double b = (double)bt2[lane] - 2.0*mh*a;
        int T, fl; mk_thresh(2.0*a, b, T, fl);
        sT2[lane] = clampT(T, 200);
        const ull fn2 = ~__ballot(fl != 0);
        if (lane == 0) sFlip2 = fn2;
    }
    __syncthreads();          // sT2 + sFlip2 + s3/q3 zeros visible
    const int T2 = sT2[lane];
    const ull flipn2 = sFlip2;
    const int n = blockIdx.x*4 + wv;
    // load own channel's 8 ull rows (coalesced: consecutive lanes 8B apart),
    // build bit-word arithmetically; byte b of row i = position i*8+b
    const ull* src = c2o + (size_t)n*512 + lane;
    uint32_t neglo = 0u, neghi = 0u;
    #pragma unroll
    for (int ii = 0; ii < 8; ++ii) {
        const ull v8 = src[(size_t)ii*64];
        const uint32_t w0 = (uint32_t)v8, w1 = (uint32_t)(v8 >> 32);
        uint32_t b8 = 0u;
        #pragma unroll
        for (int b = 0; b < 4; ++b) {
            const int v0 = (int)((int8_t)(w0 >> (8*b)));
            b8 |= ((uint32_t)(v0 - T2) >> 31) << b;          // 1 iff v<T
            const int v1 = (int)((int8_t)(w1 >> (8*b)));
            b8 |= ((uint32_t)(v1 - T2) >> 31) << (4 + b);
        }
        if (ii < 4) neglo |= b8 << (8*ii); else neghi |= b8 << (8*(ii-4));
    }
    const ull myw = ((ull)neglo | ((ull)neghi << 32)) ^ flipn2;
    // 10 outputs: popc of mismatch vs w3 words (global, L2-hot), packed reduce
    uint32_t pk[5];
    #pragma unroll
    for (int t = 0; t < 5; ++t) {
        const uint32_t pa = (uint32_t)__popcll(myw ^ w3b[(2*t+0)*64 + lane]);
        const uint32_t pb = (uint32_t)__popcll(myw ^ w3b[(2*t+1)*64 + lane]);
        pk[t] = pa | (pb << 16);
    }
    #pragma unroll
    for (int off = 32; off >= 1; off >>= 1) {
        #pragma unroll
        for (int t = 0; t < 5; ++t) pk[t] += __shfl_xor(pk[t], off);
    }
    if (lane == 0) {
        #pragma unroll
        for (int m = 0; m < 10; ++m) {
            const int tot = (pk[m >> 1] >> (16*(m & 1))) & 0xFFFF;
            fco[wv][m] = 4096 - 2*tot;
        }
    }
    __syncthreads();
    if (tid < 40) {
        const int li = tid / 10, m = tid - li*10;
        const int o = fco[li][m];
        fc[(size_t)(blockIdx.x*4 + li)*10 + m] = o;
        atomicAdd(&s3[m], o);
        atomicAdd(&q3[m], o*o);
    }
    __syncthreads();
    if (tid < 10) {
        const int shard = blockIdx.x & 7;
        atomicAdd(&stats3[(shard*10 + tid)*2 + 0], (ull)(long long)s3[tid]);
        atomicAdd(&stats3[(shard*10 + tid)*2 + 1], (ull)(long long)q3[tid]);
    }
}

// ------------------------------------------------------------------
// KD: reduce BN3 stats (per block, redundant) + apply -> d_out (fp32)
// ------------------------------------------------------------------
__global__ __launch_bounds__(256) void kD_apply(
    const int* __restrict__ fc, const float* __restrict__ gm3,
    const float* __restrict__ bt3, const ull* __restrict__ stats3,
    float* __restrict__ out)
{
    __shared__ float a3[10], b3[10];
    const int tid = threadIdx.x;
    if (tid < 10) {
        long long s = 0, q = 0;
        for (int sh = 0; sh < 8; ++sh) {
            s += (long long)stats3[(sh*10 + tid)*2 + 0];
            q += (long long)stats3[(sh*10 + tid)*2 + 1];
        }
        const double N = 8192.0;
        const double mean = (double)s / N;
        const double var  = (double)q / N - mean*mean;
        const double a = (double)gm3[tid] / sqrt(var + 1e-5);
        a3[tid] = (float)a;
        b3[tid] = (float)((double)bt3[tid] - mean*a);
    }
    __syncthreads();
    const int e = blockIdx.x*256 + tid;
    if (e < NB*10) {
        const int m = e % 10;
        out[e] = fmaf(a3[m], (float)fc[e], b3[m]);
    }
}

extern "C" void kernel_launch(void* const* d_in, const int* in_sizes, int n_in,
                              void* d_out, int out_size, void* d_ws, size_t ws_size,
                              hipStream_t stream)
{
    const float* x   = (const float*)d_in[0];
    const float* w1  = (const float*)d_in[1];
    const float* gm1 = (const float*)d_in[2];
    const float* bt1 = (const float*)d_in[3];
    const float* w2  = (const float*)d_in[4];
    const float* gm2 = (const float*)d_in[5];
    const float* bt2 = (const float*)d_in[6];
    const float* w3  = (const float*)d_in[7];
    const float* gm3 = (const float*)d_in[8];
    const float* bt3 = (const float*)d_in[9];
    char* ws = (char*)d_ws;
    int8_t* c1o = (int8_t*)(ws + OFF_C1);
    ull*    c2o = (ull*)(ws + OFF_C2);
    int*    fcb = (int*)(ws + OFF_FC);
    int*    s1  = (int*)(ws + OFF_S1);
    ull*    s2  = (ull*)(ws + OFF_S2);
    ull*    s3  = (ull*)(ws + OFF_S3);
    ull*    w2bp = (ull*)(ws + OFF_W2B);
    ull*    w3bp = (ull*)(ws + OFF_W3B);

    (void)hipMemsetAsync(ws + OFF_S1, 0, 12288, stream);
    kA_conv1<<<2053, 256, 0, stream>>>(x, w1, w2, w3, c1o, s1, w2bp, w3bp);
    kB_conv2<<<1024, 256, 0, stream>>>(c1o, s1, gm1, bt1, w2bp, c2o, s2, 0);
    kB_conv2<<<1024, 256, 0, stream>>>(c1o, s1, gm1, bt1, w2bp, c2o, s2, NB/2);
    kC_fc   <<<2048, 256, 0, stream>>>(c2o, gm2, bt2, s2, w3bp, fcb, s3);
    kD_apply<<<320,  256, 0, stream>>>(fcb, gm3, bt3, s3, (float*)d_out);
}

// Round 10
// 174.129 us; speedup vs baseline: 1.0690x; 1.0635x over previous
//
#include <hip/hip_runtime.h>
#include <stdint.h>

// Binarized ConvNet via XOR+popcount on packed bits.
// Round-10: kA de-stall pass (kA measured r9: 58us, VALUBusy 29% = stall-
// bound).  (1) x loads hoisted into xv[13] regs before the ballot loop
// (breaks 13-round load->ballot serial chain); (2) c1 written directly from
// dw[] registers inside phase B (stores spread through compute, drain under
// stats phase — T14), LDS c1-copy loop deleted; (3) outb staged via b128.
// kB back to single launch (r9 split was instrumentation only).
// BN thresholds per block by wave 0 + LDS broadcast (cross-block fence
// pattern costs ~73us/kernel — r1/r2).  kB conv2 output: [n][i][64ch] ull
// layout, direct coalesced 512B stores (r5).

#define NB 8192
typedef unsigned long long ull;

// ---- ws layout ----
#define OFF_C1  ((size_t)0)                    // int8 [NB][196pos][32ch]
#define SZ_C1   ((size_t)NB*6272)
#define OFF_C2  (OFF_C1 + SZ_C1)               // ull [NB][8i][64ch] (o/2 bytes)
#define SZ_C2   ((size_t)NB*4096)
#define OFF_FC  (OFF_C2 + SZ_C2)               // int32 [NB][10]
#define SZ_FC   ((size_t)NB*10*4)
#define OFF_S1  (OFF_FC + SZ_FC)               // int  [8][32][2]   2048 B
#define OFF_S2  (OFF_S1 + 2048)                // ull  [8][64][2]   8192 B
#define OFF_S3  (OFF_S2 + 8192)                // ull  [8][10][2]   (pad 2048)
#define OFF_W2B (OFF_S3 + 2048)                // ull w2bT[8][64] (word-idx major)
#define OFF_W3B (OFF_W2B + 4096)               // ull w3b[10][64ch], bit=pos

// exact integer threshold: bit = (v >= T) ^ flip  <=>  s*v + t > 0
__device__ inline void mk_thresh(double s, double t, int &T, int &flip) {
    if (s > 0.0) {
        int v = (int)floor(-t / s) - 2;
        for (int c = 0; c < 6; ++c) { if (s * (double)v + t > 0.0) break; ++v; }
        T = v; flip = 0;
    } else if (s < 0.0) {
        int v = (int)floor(-t / s) - 2;
        for (int c = 0; c < 6; ++c) { if (!(s * (double)v + t > 0.0)) break; ++v; }
        T = v; flip = 1;
    } else { T = -200; flip = (t > 0.0) ? 0 : 1; }
}
__device__ inline int clampT(int T, int lim) {
    return (T < -lim) ? -lim : (T > lim) ? lim : T;
}

// ------------------------------------------------------------------
// KA: conv1 (binary) + integer BN1 stats + direct-from-register c1 write.
// 1 wave = 1 image, 4/block.  Blocks >= 2048: weight packer blocks.
// ------------------------------------------------------------------
__global__ __launch_bounds__(256) void kA_conv1(
    const float* __restrict__ x, const float* __restrict__ w1,
    const float* __restrict__ w2, const float* __restrict__ w3,
    int8_t* __restrict__ c1out, int* __restrict__ stats1,
    ull* __restrict__ w2bT, ull* __restrict__ w3b)
{
    const int tid = threadIdx.x, lane = tid & 63, wv = tid >> 6;

    if (blockIdx.x >= 2048) {   // ---- parallel weight packer blocks ----
        const int t = (blockIdx.x - 2048)*256 + tid;
        if (t < 512) {
            const int idx = t >> 6, k = t & 63;
            const int u = idx >> 1, pr = idx & 1;
            uint32_t lo = 0u, hi = 0u;
            #pragma unroll 8
            for (int c = 0; c < 32; ++c) {
                const float* wp = w2 + (((k*32 + c)*4 + u)*4 + 2*pr);
                lo |= (wp[0] > 0.f ? 1u : 0u) << c;
                hi |= (wp[1] > 0.f ? 1u : 0u) << c;
            }
            w2bT[t] = (ull)lo | ((ull)hi << 32);
        } else if (t < 1152) {
            const int w = t - 512;                 // w = m*64 + ch
            const float* wp = w3 + (size_t)(w >> 6)*4096 + (size_t)(w & 63)*64;
            ull bits = 0ull;
            #pragma unroll 16
            for (int k = 0; k < 64; ++k)
                bits |= (ull)(wp[k] > 0.f ? 1 : 0) << k;
            w3b[w] = bits;
        }
        return;
    }

    __shared__ ull sxb[4][16];              // 784 input sign bits, per wave
    __shared__ uint32_t wfilt[32];          // 25-bit filters
    __shared__ uint32_t outb[4][1568];      // int8 [196][32] as dwords, per wave
    __shared__ int lsum[32], lsq[32];

    if (tid < 32) {
        uint32_t f = 0u;
        #pragma unroll
        for (int q = 0; q < 25; ++q) f |= (w1[tid*25 + q] > 0.f ? 1u : 0u) << q;
        wfilt[tid] = f;
        lsum[tid] = 0; lsq[tid] = 0;
    }
    __syncthreads();          // barrier 1: wfilt + zeroed lsum visible
    const int n = blockIdx.x*4 + wv;
    // phase A: 13 x-loads HOISTED (all in flight), then ballot rounds
    float xv[13];
    #pragma unroll
    for (int t = 0; t < 13; ++t) {
        const int idx = t*64 + lane;
        xv[t] = (idx < 784) ? x[(size_t)n*784 + idx] : -1.f;
    }
    #pragma unroll
    for (int t = 0; t < 13; ++t) {
        const ull bal = __ballot(xv[t] > 0.f);
        if (lane == t) sxb[wv][t] = bal;
    }
    if (lane == 13) sxb[wv][13] = 0ull;
    // phase B: each lane computes up to 4 positions, 32 channels each;
    // c1 stored DIRECTLY from registers (2 int4/position, spread through
    // compute); outb staged (b128) for the stats transpose.
    int4* c1dst = (int4*)(c1out + (size_t)n*6272);
    #pragma unroll
    for (int t = 0; t < 4; ++t) {
        const int p = t*64 + lane;
        if (p < 196) {
            const int i = p / 14, j = p - i*14;
            const uint32_t cmask = (j == 0) ? 0x1Cu : (j == 13) ? 0x0Fu : 0x1Fu;
            uint32_t win = 0u, vm = 0u;
            #pragma unroll
            for (int u = 0; u < 5; ++u) {
                const int r = 2*i + u - 2;
                if (r >= 0 && r < 28) {
                    const int bp = 28*r, w0 = bp >> 6, sh = bp & 63;
                    const ull a = sxb[wv][w0], b = sxb[wv][w0+1];
                    uint32_t row = (uint32_t)((a >> sh) | ((b << 1) << (63 - sh)));
                    row = (row & 0x0FFFFFFFu) << 2;
                    win |= ((row >> (2*j)) & 31u) << (5*u);
                    vm  |= cmask << (5*u);
                }
            }
            const int nv = __popc(vm);
            uint32_t dw[8];
            #pragma unroll
            for (int d = 0; d < 8; ++d) dw[d] = 0u;
            #pragma unroll
            for (int c = 0; c < 32; ++c) {
                const int diff = __popc((win ^ wfilt[c]) & vm);
                const int o = nv - 2*diff;
                dw[c >> 2] |= (uint32_t)(o & 255) << (8*(c & 3));
            }
            const int4 lo4 = make_int4((int)dw[0], (int)dw[1], (int)dw[2], (int)dw[3]);
            const int4 hi4 = make_int4((int)dw[4], (int)dw[5], (int)dw[6], (int)dw[7]);
            int4* ob4 = (int4*)&outb[wv][p*8];
            ob4[0] = lo4; ob4[1] = hi4;           // LDS staging (stats)
            c1dst[p*2]     = lo4;                 // direct global c1 write
            c1dst[p*2 + 1] = hi4;
        }
    }
    {   // stats: dword reads, lane owns channel-dword d = lane&7
        int s4[4] = {0,0,0,0}, q4[4] = {0,0,0,0};
        const uint32_t* ob32 = &outb[wv][0];
        #pragma unroll
        for (int t = 0; t < 25; ++t) {
            const int idx = t*64 + lane;
            if (idx < 1568) {
                const uint32_t dwv = ob32[idx];
                #pragma unroll
                for (int qq = 0; qq < 4; ++qq) {
                    const int v = (int)((int8_t)(dwv >> (8*qq)));
                    s4[qq] += v; q4[qq] += v*v;
                }
            }
        }
        #pragma unroll
        for (int off = 8; off <= 32; off <<= 1) {
            #pragma unroll
            for (int qq = 0; qq < 4; ++qq) {
                s4[qq] += __shfl_xor(s4[qq], off);
                q4[qq] += __shfl_xor(q4[qq], off);
            }
        }
        if (lane < 8) {
            #pragma unroll
            for (int qq = 0; qq < 4; ++qq) {
                atomicAdd(&lsum[lane*4 + qq], s4[qq]);
                atomicAdd(&lsq[lane*4 + qq], q4[qq]);
            }
        }
    }
    __syncthreads();          // barrier 2: all waves' stats in lsum/lsq
    if (tid < 32) {
        const int shard = blockIdx.x & 7;
        atomicAdd(&stats1[(shard*32 + tid)*2 + 0], lsum[tid]);
        atomicAdd(&stats1[(shard*32 + tid)*2 + 1], lsq[tid]);
    }
}

// ------------------------------------------------------------------
// KB: per-BLOCK BN1 thresholds (wave 0 computes, LDS broadcast), binarize
// c1, conv2 xor+popc with b128 register sliding window, direct coalesced
// ull stores in [n][i][64ch] layout.  1 wave = 1 image.  (r5-proven.)
// ------------------------------------------------------------------
__global__ __launch_bounds__(256) void kB_conv2(
    const int8_t* __restrict__ c1out, const int* __restrict__ stats1,
    const float* __restrict__ gm1, const float* __restrict__ bt1,
    const ull* __restrict__ w2bT,
    ull* __restrict__ c2out, ull* __restrict__ stats2)
{
    __shared__ uint32_t BwU[4][14][16]; // packed input bits, 14 used/row, pad 16
    __shared__ int sT1[32];             // per-block thresholds
    __shared__ uint32_t sFlip1;
    __shared__ int ssum[64], ssq[64];
    const int tid = threadIdx.x, lane = tid & 63, wv = tid >> 6;
    const int n = blockIdx.x*4 + wv;

    // W fragments from global (coalesced, L2-hot), split lo/hi dwords
    uint32_t Wlo[8], Whi[8];
    #pragma unroll
    for (int idx = 0; idx < 8; ++idx) {
        const uint2 w = ((const uint2*)w2bT)[idx*64 + lane];
        Wlo[idx] = w.x; Whi[idx] = w.y;
    }

    if (tid < 64) { ssum[tid] = 0; ssq[tid] = 0; }
    // per-BLOCK BN1 threshold computation (wave 0 only)
    int fl = 0;
    if (tid < 32) {
        long long s = 0, q = 0;
        for (int sh = 0; sh < 8; ++sh) {
            s += stats1[(sh*32 + tid)*2 + 0];
            q += stats1[(sh*32 + tid)*2 + 1];
        }
        const double N = 8192.0 * 196.0;
        const double mean = (double)s / N;
        const double var  = (double)q / N - mean*mean;
        const double a = (double)gm1[tid] / sqrt(var + 1e-5);
        const double b = (double)bt1[tid] - mean*a;
        int T; mk_thresh(a, b, T, fl);
        sT1[tid] = clampT(T, 26);
    }
    if (wv == 0) {
        const uint32_t fn1 = ~(uint32_t)__ballot(fl != 0);
        if (lane == 0) sFlip1 = fn1;
    }
    __syncthreads();          // barrier 1: sT1 + sFlip1 + ssum zeros visible
    const uint32_t flipn1 = sFlip1;

    // pack phase — wave-local: binarize own image's 196 positions
    for (int t = lane; t < 196; t += 64) {
        const int r = t / 14, c = t - r*14;
        const uint4* src = (const uint4*)(c1out + ((size_t)n*196 + t)*32);
        const uint4 lo4 = src[0], hi4 = src[1];
        const uint32_t wsrc[8] = {lo4.x, lo4.y, lo4.z, lo4.w, hi4.x, hi4.y, hi4.z, hi4.w};
        uint32_t neg = 0u;
        #pragma unroll
        for (int d = 0; d < 8; ++d) {
            #pragma unroll
            for (int qq = 0; qq < 4; ++qq) {
                const int ch = d*4 + qq;
                const int v = (int)((int8_t)(wsrc[d] >> (8*qq)));
                neg |= ((uint32_t)(v - sT1[ch]) >> 31) << ch;   // 1 iff v<T
            }
        }
        BwU[wv][r][c] = neg ^ flipn1;
    }

    // compute phase: lane = out-channel; b128 register sliding window.
    uint32_t PA[32], PB[32];
#define LOADP(BUF, K)                                                          \
    {                                                                          \
        const uint4* r0 = (const uint4*)&BwU[wv][2*(K)][0];                    \
        const uint4* r1 = (const uint4*)&BwU[wv][2*(K)+1][0];                  \
        _Pragma("unroll")                                                      \
        for (int tt = 0; tt < 4; ++tt) {                                       \
            const uint4 v0 = r0[tt];                                           \
            BUF[4*tt+0] = v0.x; BUF[4*tt+1] = v0.y;                            \
            BUF[4*tt+2] = v0.z; BUF[4*tt+3] = v0.w;                            \
            const uint4 v1 = r1[tt];                                           \
            BUF[16+4*tt+0] = v1.x; BUF[16+4*tt+1] = v1.y;                      \
            BUF[16+4*tt+2] = v1.z; BUF[16+4*tt+3] = v1.w;                      \
        }                                                                      \
    }
#define UT(BUF, RO, UU)                                                        \
    {                                                                          \
        if (j >= 1) { D += __popc(BUF[(RO)*16 + 2*j-2] ^ Wlo[2*(UU)])          \
                         + __popc(BUF[(RO)*16 + 2*j-1] ^ Whi[2*(UU)]);   ++nw; } \
        if (j <= 6) { D += __popc(BUF[(RO)*16 + 2*j]   ^ Wlo[2*(UU)+1])        \
                         + __popc(BUF[(RO)*16 + 2*j+1] ^ Whi[2*(UU)+1]); ++nw; } \
    }
    int s = 0, q = 0;
    ull* dst = c2out + (size_t)n*512 + lane;     // [n][i][64ch] ull layout
    LOADP(PA, 0)
    #pragma unroll
    for (int i = 0; i < 8; ++i) {
        if (i >= 1 && i <= 6) {      // prefetch pair i into alternating buffer
            if (i & 1) { LOADP(PB, i) } else { LOADP(PA, i) }
        }
        uint32_t o0 = 0u, o1 = 0u;
        #pragma unroll
        for (int j = 0; j < 8; ++j) {
            int D = 0, nw = 0;
            if (i >= 1) {            // pair i-1: rows 2i-2 (u=0), 2i-1 (u=1)
                if ((i-1) & 1) { UT(PB, 0, 0) UT(PB, 1, 1) }
                else           { UT(PA, 0, 0) UT(PA, 1, 1) }
            }
            if (i <= 6) {            // pair i:   rows 2i (u=2), 2i+1 (u=3)
                if (i & 1) { UT(PB, 0, 2) UT(PB, 1, 3) }
                else       { UT(PA, 0, 2) UT(PA, 1, 3) }
            }
            const int o = 32*nw - D;         // = full/2, exact
            s += o; q += o*o;
            if (j < 4) o0 |= (uint32_t)(o & 255) << (8*j);
            else       o1 |= (uint32_t)(o & 255) << (8*(j-4));
        }
        // direct coalesced store: consecutive lanes -> consecutive 8B
        dst[i*64] = (ull)o0 | ((ull)o1 << 32);
    }
#undef LOADP
#undef UT
    atomicAdd(&ssum[lane], s);
    atomicAdd(&ssq[lane], q);
    __syncthreads();          // barrier 2: all waves' stats in ssum/ssq
    if (tid < 64) {
        const int shard = blockIdx.x & 7;
        atomicAdd(&stats2[(shard*64 + tid)*2 + 0], (ull)(long long)ssum[tid]);
        atomicAdd(&stats2[(shard*64 + tid)*2 + 1], (ull)(long long)ssq[tid]);
    }
}

// ------------------------------------------------------------------
// KC: per-BLOCK BN2 thresholds (wave 0 computes lane=ch, LDS broadcast),
// binarize arithmetically from [n][i][64ch] ull layout, fc xor+popc,
// packed shuffle reduction, BN3 stats.  1 wave = 1 image.
// ------------------------------------------------------------------
__global__ __launch_bounds__(256) void kC_fc(
    const ull* __restrict__ c2o, const float* __restrict__ gm2,
    const float* __restrict__ bt2, const ull* __restrict__ stats2,
    const ull* __restrict__ w3b,
    int* __restrict__ fc, ull* __restrict__ stats3)
{
    __shared__ int fco[4][10];
    __shared__ int s3[10], q3[10];
    __shared__ int sT2[64];
    __shared__ ull sFlip2;
    const int tid = threadIdx.x, lane = tid & 63, wv = tid >> 6;
    if (tid < 10) { s3[tid] = 0; q3[tid] = 0; }
    // per-BLOCK BN2 thresholds: wave 0, lane = channel
    if (wv == 0) {
        long long ss = 0, qq = 0;
        for (int sh = 0; sh < 8; ++sh) {
            ss += (long long)stats2[(sh*64 + lane)*2 + 0];
            qq += (long long)stats2[(sh*64 + lane)*2 + 1];
        }
        const double N = 8192.0 * 64.0;
        const double mh = (double)ss / N;
        const double vh = (double)qq / N - mh*mh;
        const double a = (double)gm2[lane] / sqrt(4.0*vh + 1e-5);
        const double b = (double)bt2[lane] - 2.0*mh*a;
        int T, fl; mk_thresh(2.0*a, b, T, fl);
        sT2[lane] = clampT(T, 200);
        const ull fn2 = ~__ballot(fl != 0);
        if (lane == 0) sFlip2 = fn2;
    }
    __syncthreads();          // sT2 + sFlip2 + s3/q3 zeros visible
    const int T2 = sT2[lane];
    const ull flipn2 = sFlip2;
    const int n = blockIdx.x*4 + wv;
    // load own channel's 8 ull rows (coalesced: consecutive lanes 8B apart),
    // build bit-word arithmetically; byte b of row i = position i*8+b
    const ull* src = c2o + (size_t)n*512 + lane;
    uint32_t neglo = 0u, neghi = 0u;
    #pragma unroll
    for (int ii = 0; ii < 8; ++ii) {
        const ull v8 = src[(size_t)ii*64];
        const uint32_t w0 = (uint32_t)v8, w1 = (uint32_t)(v8 >> 32);
        uint32_t b8 = 0u;
        #pragma unroll
        for (int b = 0; b < 4; ++b) {
            const int v0 = (int)((int8_t)(w0 >> (8*b)));
            b8 |= ((uint32_t)(v0 - T2) >> 31) << b;          // 1 iff v<T
            const int v1 = (int)((int8_t)(w1 >> (8*b)));
            b8 |= ((uint32_t)(v1 - T2) >> 31) << (4 + b);
        }
        if (ii < 4) neglo |= b8 << (8*ii); else neghi |= b8 << (8*(ii-4));
    }
    const ull myw = ((ull)neglo | ((ull)neghi << 32)) ^ flipn2;
    // 10 outputs: popc of mismatch vs w3 words (global, L2-hot), packed reduce
    uint32_t pk[5];
    #pragma unroll
    for (int t = 0; t < 5; ++t) {
        const uint32_t pa = (uint32_t)__popcll(myw ^ w3b[(2*t+0)*64 + lane]);
        const uint32_t pb = (uint32_t)__popcll(myw ^ w3b[(2*t+1)*64 + lane]);
        pk[t] = pa | (pb << 16);
    }
    #pragma unroll
    for (int off = 32; off >= 1; off >>= 1) {
        #pragma unroll
        for (int t = 0; t < 5; ++t) pk[t] += __shfl_xor(pk[t], off);
    }
    if (lane == 0) {
        #pragma unroll
        for (int m = 0; m < 10; ++m) {
            const int tot = (pk[m >> 1] >> (16*(m & 1))) & 0xFFFF;
            fco[wv][m] = 4096 - 2*tot;
        }
    }
    __syncthreads();
    if (tid < 40) {
        const int li = tid / 10, m = tid - li*10;
        const int o = fco[li][m];
        fc[(size_t)(blockIdx.x*4 + li)*10 + m] = o;
        atomicAdd(&s3[m], o);
        atomicAdd(&q3[m], o*o);
    }
    __syncthreads();
    if (tid < 10) {
        const int shard = blockIdx.x & 7;
        atomicAdd(&stats3[(shard*10 + tid)*2 + 0], (ull)(long long)s3[tid]);
        atomicAdd(&stats3[(shard*10 + tid)*2 + 1], (ull)(long long)q3[tid]);
    }
}

// ------------------------------------------------------------------
// KD: reduce BN3 stats (per block, redundant) + apply -> d_out (fp32)
// ------------------------------------------------------------------
__global__ __launch_bounds__(256) void kD_apply(
    const int* __restrict__ fc, const float* __restrict__ gm3,
    const float* __restrict__ bt3, const ull* __restrict__ stats3,
    float* __restrict__ out)
{
    __shared__ float a3[10], b3[10];
    const int tid = threadIdx.x;
    if (tid < 10) {
        long long s = 0, q = 0;
        for (int sh = 0; sh < 8; ++sh) {
            s += (long long)stats3[(sh*10 + tid)*2 + 0];
            q += (long long)stats3[(sh*10 + tid)*2 + 1];
        }
        const double N = 8192.0;
        const double mean = (double)s / N;
        const double var  = (double)q / N - mean*mean;
        const double a = (double)gm3[tid] / sqrt(var + 1e-5);
        a3[tid] = (float)a;
        b3[tid] = (float)((double)bt3[tid] - mean*a);
    }
    __syncthreads();
    const int e = blockIdx.x*256 + tid;
    if (e < NB*10) {
        const int m = e % 10;
        out[e] = fmaf(a3[m], (float)fc[e], b3[m]);
    }
}

extern "C" void kernel_launch(void* const* d_in, const int* in_sizes, int n_in,
                              void* d_out, int out_size, void* d_ws, size_t ws_size,
                              hipStream_t stream)
{
    const float* x   = (const float*)d_in[0];
    const float* w1  = (const float*)d_in[1];
    const float* gm1 = (const float*)d_in[2];
    const float* bt1 = (const float*)d_in[3];
    const float* w2  = (const float*)d_in[4];
    const float* gm2 = (const float*)d_in[5];
    const float* bt2 = (const float*)d_in[6];
    const float* w3  = (const float*)d_in[7];
    const float* gm3 = (const float*)d_in[8];
    const float* bt3 = (const float*)d_in[9];
    char* ws = (char*)d_ws;
    int8_t* c1o = (int8_t*)(ws + OFF_C1);
    ull*    c2o = (ull*)(ws + OFF_C2);
    int*    fcb = (int*)(ws + OFF_FC);
    int*    s1  = (int*)(ws + OFF_S1);
    ull*    s2  = (ull*)(ws + OFF_S2);
    ull*    s3  = (ull*)(ws + OFF_S3);
    ull*    w2bp = (ull*)(ws + OFF_W2B);
    ull*    w3bp = (ull*)(ws + OFF_W3B);

    (void)hipMemsetAsync(ws + OFF_S1, 0, 12288, stream);
    kA_conv1<<<2053, 256, 0, stream>>>(x, w1, w2, w3, c1o, s1, w2bp, w3bp);
    kB_conv2<<<2048, 256, 0, stream>>>(c1o, s1, gm1, bt1, w2bp, c2o, s2);
    kC_fc   <<<2048, 256, 0, stream>>>(c2o, gm2, bt2, s2, w3bp, fcb, s3);
    kD_apply<<<320,  256, 0, stream>>>(fcb, gm3, bt3, s3, (float*)d_out);
}